// Round 6
// baseline (303.148 us; speedup 1.0000x reference)
//
#include <hip/hip_runtime.h>

typedef _Float16 f16;
typedef __attribute__((ext_vector_type(8))) _Float16 h8;
typedef __attribute__((ext_vector_type(4))) _Float16 h4;
typedef __attribute__((ext_vector_type(4))) float f4;

#define MFMA(a, b, c) __builtin_amdgcn_mfma_f32_16x16x32_f16(a, b, c, 0, 0, 0)

// Q prescale: 1/sqrt(64) * log2(e), folded into qkv epilogue -> softmax in base-2
#define QSCALE 0.18033688011112042f

__device__ __forceinline__ void gload16(const void* g, void* l) {
    __builtin_amdgcn_global_load_lds((const __attribute__((address_space(1))) void*)g,
                                     (__attribute__((address_space(3))) void*)l, 16, 0, 0);
}

__device__ __forceinline__ float fexp2(float x) {
    float r;
    asm("v_exp_f32 %0, %1" : "=v"(r) : "v"(x));
    return r;
}

__device__ __forceinline__ float rmax16(float v) {
#pragma unroll
    for (int m = 1; m < 16; m <<= 1) v = fmaxf(v, __shfl_xor(v, m));
    return v;
}
__device__ __forceinline__ float rsum16(float v) {
#pragma unroll
    for (int m = 1; m < 16; m <<= 1) v += __shfl_xor(v, m);
    return v;
}

// ---------------- conversion kernels ----------------

__global__ __launch_bounds__(256) void cvt_f16_kernel(const float* __restrict__ in,
                                                      f16* __restrict__ out, int n8) {
    int i = blockIdx.x * blockDim.x + threadIdx.x;
    if (i >= n8) return;
    const float4* p = (const float4*)in + (size_t)i * 2;
    float4 a = p[0], b = p[1];
    h8 o;
    o[0] = (f16)a.x; o[1] = (f16)a.y; o[2] = (f16)a.z; o[3] = (f16)a.w;
    o[4] = (f16)b.x; o[5] = (f16)b.y; o[6] = (f16)b.z; o[7] = (f16)b.w;
    *((h8*)out + i) = o;
}

// in: [R][Cc] f32 row-major -> out: [Cc][R] f16 row-major
__global__ __launch_bounds__(256) void transpose_cvt(const float* __restrict__ in,
                                                     f16* __restrict__ out, int R, int Cc) {
    __shared__ float tile[32][33];
    int tx = threadIdx.x, ty = threadIdx.y;
    int c0 = blockIdx.x * 32, r0 = blockIdx.y * 32;
#pragma unroll
    for (int k = 0; k < 32; k += 8)
        tile[ty + k][tx] = in[(size_t)(r0 + ty + k) * Cc + c0 + tx];
    __syncthreads();
#pragma unroll
    for (int k = 0; k < 32; k += 8)
        out[(size_t)(c0 + ty + k) * R + r0 + tx] = (f16)tile[tx][ty + k];
}

// ---------------- GEMM core (128x128 tile, BK=64, 4 waves, swizzled LDS) ----------------

__device__ __forceinline__ void gemm_core(const f16* __restrict__ A, const f16* __restrict__ Bt,
                                          int K, int m0, int n0,
                                          f16* lA, f16* lB, f4 acc[4][4]) {
    const int tid = threadIdx.x, lane = tid & 63, wave = tid >> 6;
    const int wm = (wave >> 1) * 64, wn = (wave & 1) * 64;
    for (int k0 = 0; k0 < K; k0 += 64) {
        __syncthreads();
#pragma unroll
        for (int i = 0; i < 4; i++) {
            int s = i * 256 + wave * 64 + lane;
            int row = s >> 3;
            int gc = ((s & 7) ^ (row & 7)) * 8;
            gload16(A + (size_t)(m0 + row) * K + k0 + gc, lA + (i * 256 + wave * 64) * 8);
        }
#pragma unroll
        for (int i = 0; i < 4; i++) {
            int s = i * 256 + wave * 64 + lane;
            int row = s >> 3;
            int gc = ((s & 7) ^ (row & 7)) * 8;
            gload16(Bt + (size_t)(n0 + row) * K + k0 + gc, lB + (i * 256 + wave * 64) * 8);
        }
        __syncthreads();
#pragma unroll
        for (int kk = 0; kk < 2; kk++) {
            h8 af[4], bg[4];
#pragma unroll
            for (int im = 0; im < 4; im++) {
                int row = wm + im * 16 + (lane & 15);
                int pc = (kk * 4 + (lane >> 4)) ^ (row & 7);
                af[im] = *(const h8*)(lA + row * 64 + pc * 8);
            }
#pragma unroll
            for (int in = 0; in < 4; in++) {
                int row = wn + in * 16 + (lane & 15);
                int pc = (kk * 4 + (lane >> 4)) ^ (row & 7);
                bg[in] = *(const h8*)(lB + row * 64 + pc * 8);
            }
#pragma unroll
            for (int im = 0; im < 4; im++)
#pragma unroll
                for (int in = 0; in < 4; in++)
                    acc[im][in] = MFMA(af[im], bg[in], acc[im][in]);
        }
    }
}

// ---------------- QKV GEMM: writes Q (prescaled), K [BH][T][64], V^T [BH][64][T] ----------------

__global__ __launch_bounds__(256) void qkv_gemm(const f16* __restrict__ A, const f16* __restrict__ Bt,
                                                const float* __restrict__ bias,
                                                f16* __restrict__ Qo, f16* __restrict__ Ko,
                                                f16* __restrict__ Vo) {
    __shared__ f16 lA[128 * 64], lB[128 * 64];
    f4 acc[4][4];
    const f4 zz = {0.f, 0.f, 0.f, 0.f};
#pragma unroll
    for (int i = 0; i < 4; i++)
#pragma unroll
        for (int j = 0; j < 4; j++) acc[i][j] = zz;

    const int swz = (blockIdx.x & 7) * 192 + (blockIdx.x >> 3);  // XCD-chunked (1536 = 8*192)
    const int nb = swz % 24, mb = swz / 24;
    gemm_core(A, Bt, 1024, mb * 128, nb * 128, lA, lB, acc);

    const int lane = threadIdx.x & 63, wave = threadIdx.x >> 6;
    const int wm = (wave >> 1) * 64, wn = (wave & 1) * 64;
#pragma unroll
    for (int im = 0; im < 4; im++) {
        int m4 = mb * 128 + wm + im * 16 + (lane >> 4) * 4;
        int b = m4 >> 11, t0 = m4 & 2047;
#pragma unroll
        for (int in = 0; in < 4; in++) {
            int n = nb * 128 + wn + in * 16 + (lane & 15);
            float bb = bias[n];
            int sec = n >> 10, cc = n & 1023, hh = cc >> 6, d = cc & 63;
            if (sec == 2) {
                h4 pv;
#pragma unroll
                for (int r = 0; r < 4; r++) pv[r] = (f16)(acc[im][in][r] + bb);
                *(h4*)(Vo + ((size_t)(b * 16 + hh) * 64 + d) * 2048 + t0) = pv;
            } else {
                f16* dst = sec ? Ko : Qo;
                float sc = sec ? 1.0f : QSCALE;  // Q prescaled for base-2 softmax
                size_t base = ((size_t)(b * 16 + hh) * 2048 + t0) * 64 + d;
#pragma unroll
                for (int r = 0; r < 4; r++)
                    dst[base + (size_t)r * 64] = (f16)((acc[im][in][r] + bb) * sc);
            }
        }
    }
}

// ---------------- Proj GEMM: f32 output + bias ----------------

__global__ __launch_bounds__(256) void proj_gemm(const f16* __restrict__ A, const f16* __restrict__ Bt,
                                                 const float* __restrict__ bias,
                                                 float* __restrict__ out) {
    __shared__ f16 lA[128 * 64], lB[128 * 64];
    f4 acc[4][4];
    const f4 zz = {0.f, 0.f, 0.f, 0.f};
#pragma unroll
    for (int i = 0; i < 4; i++)
#pragma unroll
        for (int j = 0; j < 4; j++) acc[i][j] = zz;

    const int swz = (blockIdx.x & 7) * 64 + (blockIdx.x >> 3);  // XCD-chunked (512 = 8*64)
    const int nb = swz & 7, mb = swz >> 3;
    gemm_core(A, Bt, 1024, mb * 128, nb * 128, lA, lB, acc);

    const int lane = threadIdx.x & 63, wave = threadIdx.x >> 6;
    const int wm = (wave >> 1) * 64, wn = (wave & 1) * 64;
#pragma unroll
    for (int im = 0; im < 4; im++) {
        int m4 = mb * 128 + wm + im * 16 + (lane >> 4) * 4;
#pragma unroll
        for (int in = 0; in < 4; in++) {
            int n = nb * 128 + wn + in * 16 + (lane & 15);
            float bb = bias[n];
#pragma unroll
            for (int r = 0; r < 4; r++)
                out[(size_t)(m4 + r) * 1024 + n] = acc[im][in][r] + bb;
        }
    }
}

// ---------------- Flash attention (causal, base-2, defer-max, UNIFORM-WORK pairs) ----------------
// Q(prescaled),K: [BH][2048][64] f16; Vg: [BH][64][2048] f16 (transposed); O: [B][2048][1024] f16
// Grid 512 = 64 bh x 8 pairs. One block processes the causal-complementary q-tile pair
// (15-pr, pr) sequentially -> EVERY wave does exactly 34 K-tiles (uniform by construction,
// no block->CU mapping assumption). Heavy phase first.
// Round-4 pipeline per phase: K double-buffered LDS (1 tile ahead, counted vmcnt(2));
// V fragments issued right after the barrier (latency covered by QK+softmax), consumed at PV.

#define ASM_VMCNT(N) asm volatile("s_waitcnt vmcnt(" #N ")" ::: "memory")

__global__ __launch_bounds__(256) void attn_kernel(const f16* __restrict__ Q, const f16* __restrict__ K,
                                                   const f16* __restrict__ Vg, f16* __restrict__ O) {
    __shared__ f16 lK[2][64 * 64];
    __shared__ f16 lP[4 * 32 * 64];
    const int tid = threadIdx.x, lane = tid & 63, wave = tid >> 6;
    const int bh = blockIdx.x & 63;
    const int pr = blockIdx.x >> 6;  // 0..7
    const f16* Qb = Q + (size_t)bh * 2048 * 64;
    const f16* Kb = K + (size_t)bh * 2048 * 64;
    const f16* Vb = Vg + (size_t)bh * 64 * 2048;
    f16* lPw = lP + wave * 32 * 64;
    const int b = bh >> 4, hh = bh & 15;

    for (int ph = 0; ph < 2; ph++) {
        const int qb = ph ? pr : 15 - pr;  // heavy first; total work uniform across blocks
        const int q0 = qb * 128;
        const int qw = q0 + wave * 32;

        // hoist Q fragments (A-operand layout)
        h8 qf[2][2];
#pragma unroll
        for (int im = 0; im < 2; im++)
#pragma unroll
            for (int kk = 0; kk < 2; kk++) {
                int t = qw + im * 16 + (lane & 15);
                qf[im][kk] = *(const h8*)(Qb + (size_t)t * 64 + kk * 32 + (lane >> 4) * 8);
            }

        float mrun[2][4], lpart[2][4];
        f4 yacc[2][4];
        const f4 zz = {0.f, 0.f, 0.f, 0.f};
#pragma unroll
        for (int im = 0; im < 2; im++) {
#pragma unroll
            for (int r = 0; r < 4; r++) { mrun[im][r] = -3e38f; lpart[im][r] = 0.f; }
#pragma unroll
            for (int dn = 0; dn < 4; dn++) yacc[im][dn] = zz;
        }

        const int nt = q0 / 64 + 2;

        // prologue: stage K tile 0 into buffer 0
#pragma unroll
        for (int i = 0; i < 2; i++) {
            int s = i * 256 + wave * 64 + lane;
            int row = s >> 3;
            int gc = ((s & 7) ^ (row & 7)) * 8;
            gload16(Kb + (size_t)row * 64 + gc, &lK[0][(i * 256 + wave * 64) * 8]);
        }

        for (int it = 0; it < nt; it++) {
            const int cur = it & 1;
            const int k0 = it * 64;

            if (it + 1 < nt) {
#pragma unroll
                for (int i = 0; i < 2; i++) {
                    int s = i * 256 + wave * 64 + lane;
                    int row = s >> 3;
                    int gc = ((s & 7) ^ (row & 7)) * 8;
                    gload16(Kb + (size_t)(k0 + 64 + row) * 64 + gc,
                            &lK[cur ^ 1][(i * 256 + wave * 64) * 8]);
                }
                ASM_VMCNT(2);  // wait only for current tile's 2 loads
            } else {
                ASM_VMCNT(0);
            }
            __builtin_amdgcn_sched_barrier(0);
            __builtin_amdgcn_s_barrier();
            __builtin_amdgcn_sched_barrier(0);

            // issue V fragment loads EARLY (consumed at PV; QK+softmax covers L2 latency)
            h8 vf[2][4];
#pragma unroll
            for (int kk = 0; kk < 2; kk++)
#pragma unroll
                for (int dn = 0; dn < 4; dn++)
                    vf[kk][dn] = *(const h8*)(Vb + (size_t)(dn * 16 + (lane & 15)) * 2048 + k0 +
                                              kk * 32 + (lane >> 4) * 8);

            // S = Q K^T  (pre-scaled: S already in log2 units)
            f4 sacc[2][4];
#pragma unroll
            for (int im = 0; im < 2; im++)
#pragma unroll
                for (int in = 0; in < 4; in++) sacc[im][in] = zz;
            __builtin_amdgcn_s_setprio(1);
#pragma unroll
            for (int kk = 0; kk < 2; kk++) {
                h8 kf[4];
#pragma unroll
                for (int in = 0; in < 4; in++) {
                    int row = in * 16 + (lane & 15);
                    int pc = (kk * 4 + (lane >> 4)) ^ (row & 7);
                    kf[in] = *(const h8*)(&lK[cur][0] + row * 64 + pc * 8);
                }
#pragma unroll
                for (int im = 0; im < 2; im++)
#pragma unroll
                    for (int in = 0; in < 4; in++)
                        sacc[im][in] = MFMA(qf[im][kk], kf[in], sacc[im][in]);
            }
            __builtin_amdgcn_s_setprio(0);

            const bool msk = (k0 + 63 > qw);
            if (msk) {
#pragma unroll
                for (int im = 0; im < 2; im++)
#pragma unroll
                    for (int in = 0; in < 4; in++)
#pragma unroll
                        for (int r = 0; r < 4; r++) {
                            int q = qw + im * 16 + (lane >> 4) * 4 + r;
                            int k = k0 + in * 16 + (lane & 15);
                            if (k > q) sacc[im][in][r] = -3e38f;
                        }
            }

#pragma unroll
            for (int im = 0; im < 2; im++) {
#pragma unroll
                for (int r = 0; r < 4; r++) {
                    float a0 = fmaxf(sacc[im][0][r], sacc[im][1][r]);
                    float a1 = fmaxf(sacc[im][2][r], sacc[im][3][r]);
                    float vmax4 = fmaxf(a0, a1);
                    if (!__all(vmax4 <= mrun[im][r] + 8.0f)) {
                        float vmax = rmax16(vmax4);
                        float mnew = fmaxf(mrun[im][r], vmax);
                        float sc = fexp2(mrun[im][r] - mnew);
                        lpart[im][r] *= sc;
#pragma unroll
                        for (int dn = 0; dn < 4; dn++) yacc[im][dn][r] *= sc;
                        mrun[im][r] = mnew;
                    }
                    float m = mrun[im][r];
                    float ls = 0.f;
#pragma unroll
                    for (int in = 0; in < 4; in++) {
                        float p = fexp2(sacc[im][in][r] - m);
                        sacc[im][in][r] = p;
                        ls += p;
                    }
                    lpart[im][r] += ls;
                }
            }

            // write P (f16) to per-wave swizzled LDS (same-wave round trip)
#pragma unroll
            for (int im = 0; im < 2; im++)
#pragma unroll
                for (int in = 0; in < 4; in++)
#pragma unroll
                    for (int r = 0; r < 4; r++) {
                        int row = im * 16 + (lane >> 4) * 4 + r;
                        int col = in * 16 + (lane & 15);
                        lPw[row * 64 + (((col >> 3) ^ (row & 7)) * 8) + (col & 7)] =
                            (f16)sacc[im][in][r];
                    }

            // Y += P V  (V already in registers)
            __builtin_amdgcn_s_setprio(1);
#pragma unroll
            for (int kk = 0; kk < 2; kk++) {
                h8 pf[2];
#pragma unroll
                for (int im = 0; im < 2; im++) {
                    int row = im * 16 + (lane & 15);
                    int pc = (kk * 4 + (lane >> 4)) ^ (row & 7);
                    pf[im] = *(const h8*)(lPw + row * 64 + pc * 8);
                }
#pragma unroll
                for (int im = 0; im < 2; im++)
#pragma unroll
                    for (int dn = 0; dn < 4; dn++)
                        yacc[im][dn] = MFMA(pf[im], vf[kk][dn], yacc[im][dn]);
            }
            __builtin_amdgcn_s_setprio(0);

            // drain LDS reads before other waves may overwrite lK[cur] next iteration
            asm volatile("s_waitcnt lgkmcnt(0)" ::: "memory");
            __builtin_amdgcn_sched_barrier(0);
            __builtin_amdgcn_s_barrier();
            __builtin_amdgcn_sched_barrier(0);
        }

        // phase epilogue: normalize + store
#pragma unroll
        for (int im = 0; im < 2; im++) {
#pragma unroll
            for (int r = 0; r < 4; r++) {
                float inv = 1.0f / rsum16(lpart[im][r]);
#pragma unroll
                for (int dn = 0; dn < 4; dn++) {
                    int q = qw + im * 16 + (lane >> 4) * 4 + r;
                    int d = dn * 16 + (lane & 15);
                    O[((size_t)(b * 2048 + q)) * 1024 + hh * 64 + d] =
                        (f16)(yacc[im][dn][r] * inv);
                }
            }
        }
    }
}

// ---------------- launch ----------------

extern "C" void kernel_launch(void* const* d_in, const int* in_sizes, int n_in,
                              void* d_out, int out_size, void* d_ws, size_t ws_size,
                              hipStream_t stream) {
    const float* x      = (const float*)d_in[0];
    const float* W_attn = (const float*)d_in[1];
    const float* b_attn = (const float*)d_in[2];
    const float* W_proj = (const float*)d_in[3];
    const float* b_proj = (const float*)d_in[4];
    float* out = (float*)d_out;

    char* ws = (char*)d_ws;
    f16* xb  = (f16*)ws;                                   // 16 MB (reused as attn out)
    f16* Wat = (f16*)(ws + 16777216);                      // 6 MB
    f16* Wpt = (f16*)(ws + 16777216 + 6291456);            // 2 MB
    f16* Vt  = (f16*)(ws + 16777216 + 6291456 + 2097152);  // 16 MB
    f16* Qs  = (f16*)d_out;                                // scratch: first 16 MB of out
    f16* Ks  = (f16*)((char*)d_out + 16777216);            // scratch: second 16 MB of out

    cvt_f16_kernel<<<4096, 256, 0, stream>>>(x, xb, 1048576);
    transpose_cvt<<<dim3(96, 32), dim3(32, 8), 0, stream>>>(W_attn, Wat, 1024, 3072);
    transpose_cvt<<<dim3(32, 32), dim3(32, 8), 0, stream>>>(W_proj, Wpt, 1024, 1024);
    qkv_gemm<<<1536, 256, 0, stream>>>(xb, Wat, b_attn, Qs, Ks, Vt);
    attn_kernel<<<512, 256, 0, stream>>>(Qs, Ks, Vt, xb);
    proj_gemm<<<512, 256, 0, stream>>>(xb, Wpt, b_proj, out);
}

// Round 7
// 242.540 us; speedup vs baseline: 1.2499x; 1.2499x over previous
//
#include <hip/hip_runtime.h>

typedef _Float16 f16;
typedef __attribute__((ext_vector_type(8))) _Float16 h8;
typedef __attribute__((ext_vector_type(4))) _Float16 h4;
typedef __attribute__((ext_vector_type(4))) float f4;

#define MFMA(a, b, c) __builtin_amdgcn_mfma_f32_16x16x32_f16(a, b, c, 0, 0, 0)

// Q prescale: 1/sqrt(64) * log2(e), folded into qkv epilogue -> softmax in base-2
#define QSCALE 0.18033688011112042f

__device__ __forceinline__ void gload16(const void* g, void* l) {
    __builtin_amdgcn_global_load_lds((const __attribute__((address_space(1))) void*)g,
                                     (__attribute__((address_space(3))) void*)l, 16, 0, 0);
}

__device__ __forceinline__ float fexp2(float x) {
    float r;
    asm("v_exp_f32 %0, %1" : "=v"(r) : "v"(x));
    return r;
}

__device__ __forceinline__ float rmax16(float v) {
#pragma unroll
    for (int m = 1; m < 16; m <<= 1) v = fmaxf(v, __shfl_xor(v, m));
    return v;
}
__device__ __forceinline__ float rsum16(float v) {
#pragma unroll
    for (int m = 1; m < 16; m <<= 1) v += __shfl_xor(v, m);
    return v;
}

// ---------------- conversion kernels ----------------

__global__ __launch_bounds__(256) void cvt_f16_kernel(const float* __restrict__ in,
                                                      f16* __restrict__ out, int n8) {
    int i = blockIdx.x * blockDim.x + threadIdx.x;
    if (i >= n8) return;
    const float4* p = (const float4*)in + (size_t)i * 2;
    float4 a = p[0], b = p[1];
    h8 o;
    o[0] = (f16)a.x; o[1] = (f16)a.y; o[2] = (f16)a.z; o[3] = (f16)a.w;
    o[4] = (f16)b.x; o[5] = (f16)b.y; o[6] = (f16)b.z; o[7] = (f16)b.w;
    *((h8*)out + i) = o;
}

// in: [R][Cc] f32 row-major -> out: [Cc][R] f16 row-major
__global__ __launch_bounds__(256) void transpose_cvt(const float* __restrict__ in,
                                                     f16* __restrict__ out, int R, int Cc) {
    __shared__ float tile[32][33];
    int tx = threadIdx.x, ty = threadIdx.y;
    int c0 = blockIdx.x * 32, r0 = blockIdx.y * 32;
#pragma unroll
    for (int k = 0; k < 32; k += 8)
        tile[ty + k][tx] = in[(size_t)(r0 + ty + k) * Cc + c0 + tx];
    __syncthreads();
#pragma unroll
    for (int k = 0; k < 32; k += 8)
        out[(size_t)(c0 + ty + k) * R + r0 + tx] = (f16)tile[tx][ty + k];
}

// ---------------- GEMM core (128x128 tile, BK=64, 4 waves, swizzled LDS) ----------------

__device__ __forceinline__ void gemm_core(const f16* __restrict__ A, const f16* __restrict__ Bt,
                                          int K, int m0, int n0,
                                          f16* lA, f16* lB, f4 acc[4][4]) {
    const int tid = threadIdx.x, lane = tid & 63, wave = tid >> 6;
    const int wm = (wave >> 1) * 64, wn = (wave & 1) * 64;
    for (int k0 = 0; k0 < K; k0 += 64) {
        __syncthreads();
#pragma unroll
        for (int i = 0; i < 4; i++) {
            int s = i * 256 + wave * 64 + lane;
            int row = s >> 3;
            int gc = ((s & 7) ^ (row & 7)) * 8;
            gload16(A + (size_t)(m0 + row) * K + k0 + gc, lA + (i * 256 + wave * 64) * 8);
        }
#pragma unroll
        for (int i = 0; i < 4; i++) {
            int s = i * 256 + wave * 64 + lane;
            int row = s >> 3;
            int gc = ((s & 7) ^ (row & 7)) * 8;
            gload16(Bt + (size_t)(n0 + row) * K + k0 + gc, lB + (i * 256 + wave * 64) * 8);
        }
        __syncthreads();
#pragma unroll
        for (int kk = 0; kk < 2; kk++) {
            h8 af[4], bg[4];
#pragma unroll
            for (int im = 0; im < 4; im++) {
                int row = wm + im * 16 + (lane & 15);
                int pc = (kk * 4 + (lane >> 4)) ^ (row & 7);
                af[im] = *(const h8*)(lA + row * 64 + pc * 8);
            }
#pragma unroll
            for (int in = 0; in < 4; in++) {
                int row = wn + in * 16 + (lane & 15);
                int pc = (kk * 4 + (lane >> 4)) ^ (row & 7);
                bg[in] = *(const h8*)(lB + row * 64 + pc * 8);
            }
#pragma unroll
            for (int im = 0; im < 4; im++)
#pragma unroll
                for (int in = 0; in < 4; in++)
                    acc[im][in] = MFMA(af[im], bg[in], acc[im][in]);
        }
    }
}

// ---------------- QKV GEMM: writes Q (prescaled), K [BH][T][64], V^T [BH][64][T] ----------------

__global__ __launch_bounds__(256) void qkv_gemm(const f16* __restrict__ A, const f16* __restrict__ Bt,
                                                const float* __restrict__ bias,
                                                f16* __restrict__ Qo, f16* __restrict__ Ko,
                                                f16* __restrict__ Vo) {
    __shared__ f16 lA[128 * 64], lB[128 * 64];
    f4 acc[4][4];
    const f4 zz = {0.f, 0.f, 0.f, 0.f};
#pragma unroll
    for (int i = 0; i < 4; i++)
#pragma unroll
        for (int j = 0; j < 4; j++) acc[i][j] = zz;

    const int swz = (blockIdx.x & 7) * 192 + (blockIdx.x >> 3);  // XCD-chunked (1536 = 8*192)
    const int nb = swz % 24, mb = swz / 24;
    gemm_core(A, Bt, 1024, mb * 128, nb * 128, lA, lB, acc);

    const int lane = threadIdx.x & 63, wave = threadIdx.x >> 6;
    const int wm = (wave >> 1) * 64, wn = (wave & 1) * 64;
#pragma unroll
    for (int im = 0; im < 4; im++) {
        int m4 = mb * 128 + wm + im * 16 + (lane >> 4) * 4;
        int b = m4 >> 11, t0 = m4 & 2047;
#pragma unroll
        for (int in = 0; in < 4; in++) {
            int n = nb * 128 + wn + in * 16 + (lane & 15);
            float bb = bias[n];
            int sec = n >> 10, cc = n & 1023, hh = cc >> 6, d = cc & 63;
            if (sec == 2) {
                h4 pv;
#pragma unroll
                for (int r = 0; r < 4; r++) pv[r] = (f16)(acc[im][in][r] + bb);
                *(h4*)(Vo + ((size_t)(b * 16 + hh) * 64 + d) * 2048 + t0) = pv;
            } else {
                f16* dst = sec ? Ko : Qo;
                float sc = sec ? 1.0f : QSCALE;  // Q prescaled for base-2 softmax
                size_t base = ((size_t)(b * 16 + hh) * 2048 + t0) * 64 + d;
#pragma unroll
                for (int r = 0; r < 4; r++)
                    dst[base + (size_t)r * 64] = (f16)((acc[im][in][r] + bb) * sc);
            }
        }
    }
}

// ---------------- Proj GEMM: f32 output + bias ----------------

__global__ __launch_bounds__(256) void proj_gemm(const f16* __restrict__ A, const f16* __restrict__ Bt,
                                                 const float* __restrict__ bias,
                                                 float* __restrict__ out) {
    __shared__ f16 lA[128 * 64], lB[128 * 64];
    f4 acc[4][4];
    const f4 zz = {0.f, 0.f, 0.f, 0.f};
#pragma unroll
    for (int i = 0; i < 4; i++)
#pragma unroll
        for (int j = 0; j < 4; j++) acc[i][j] = zz;

    const int swz = (blockIdx.x & 7) * 64 + (blockIdx.x >> 3);  // XCD-chunked (512 = 8*64)
    const int nb = swz & 7, mb = swz >> 3;
    gemm_core(A, Bt, 1024, mb * 128, nb * 128, lA, lB, acc);

    const int lane = threadIdx.x & 63, wave = threadIdx.x >> 6;
    const int wm = (wave >> 1) * 64, wn = (wave & 1) * 64;
#pragma unroll
    for (int im = 0; im < 4; im++) {
        int m4 = mb * 128 + wm + im * 16 + (lane >> 4) * 4;
#pragma unroll
        for (int in = 0; in < 4; in++) {
            int n = nb * 128 + wn + in * 16 + (lane & 15);
            float bb = bias[n];
#pragma unroll
            for (int r = 0; r < 4; r++)
                out[(size_t)(m4 + r) * 1024 + n] = acc[im][in][r] + bb;
        }
    }
}

// ---------------- Flash attention (causal, base-2, defer-max, 3-buf single-barrier) ----------------
// Q(prescaled),K: [BH][2048][64] f16; Vg: [BH][64][2048] f16 (transposed); O: [B][2048][1024] f16
// Grid 1024: 1 block = 128 q-rows; 4 waves x 32 rows; KV tiles of 64; balance permutation.
// K TRIPLE-buffered via global_load_lds + counted vmcnt(2) -> ONE barrier per tile:
//   stage(it+1 -> buf[(it+1)%3]) | vmcnt(2) | s_barrier | compute from buf[it%3].
//   Clobber of buf[it%3] (stage at it+2) is fenced by barrier it+1, which the slowest
//   wave reaches only after its it-compute MFMAs consumed their ds_reads. No LDS drain.
// V fragments direct from global at PV (L2-resident panel).

#define ASM_VMCNT(N) asm volatile("s_waitcnt vmcnt(" #N ")" ::: "memory")

__global__ __launch_bounds__(256) void attn_kernel(const f16* __restrict__ Q, const f16* __restrict__ K,
                                                   const f16* __restrict__ Vg, f16* __restrict__ O) {
    __shared__ f16 lK[3][64 * 64];
    __shared__ f16 lP[4 * 32 * 64];
    const int tid = threadIdx.x, lane = tid & 63, wave = tid >> 6;
    const int bh = blockIdx.x & 63;
    const int g = blockIdx.x >> 6;
    const int qb = (int)((0x75318ACE64209BDFull >> (g * 4)) & 15);
    const int q0 = qb * 128;
    const int qw = q0 + wave * 32;
    const f16* Qb = Q + (size_t)bh * 2048 * 64;
    const f16* Kb = K + (size_t)bh * 2048 * 64;
    const f16* Vb = Vg + (size_t)bh * 64 * 2048;
    f16* lPw = lP + wave * 32 * 64;

    // hoist Q fragments (A-operand layout)
    h8 qf[2][2];
#pragma unroll
    for (int im = 0; im < 2; im++)
#pragma unroll
        for (int kk = 0; kk < 2; kk++) {
            int t = qw + im * 16 + (lane & 15);
            qf[im][kk] = *(const h8*)(Qb + (size_t)t * 64 + kk * 32 + (lane >> 4) * 8);
        }

    float mrun[2][4], lpart[2][4];
    f4 yacc[2][4];
    const f4 zz = {0.f, 0.f, 0.f, 0.f};
#pragma unroll
    for (int im = 0; im < 2; im++) {
#pragma unroll
        for (int r = 0; r < 4; r++) { mrun[im][r] = -3e38f; lpart[im][r] = 0.f; }
#pragma unroll
        for (int dn = 0; dn < 4; dn++) yacc[im][dn] = zz;
    }

    const int nt = q0 / 64 + 2;

    // prologue: stage K tile 0 into buffer 0
#pragma unroll
    for (int i = 0; i < 2; i++) {
        int s = i * 256 + wave * 64 + lane;
        int row = s >> 3;
        int gc = ((s & 7) ^ (row & 7)) * 8;
        gload16(Kb + (size_t)row * 64 + gc, &lK[0][(i * 256 + wave * 64) * 8]);
    }

    int cur = 0;
    for (int it = 0; it < nt; it++) {
        const int k0 = it * 64;
        int nxt = cur + 1;
        if (nxt == 3) nxt = 0;

        if (it + 1 < nt) {
#pragma unroll
            for (int i = 0; i < 2; i++) {
                int s = i * 256 + wave * 64 + lane;
                int row = s >> 3;
                int gc = ((s & 7) ^ (row & 7)) * 8;
                gload16(Kb + (size_t)(k0 + 64 + row) * 64 + gc,
                        &lK[nxt][(i * 256 + wave * 64) * 8]);
            }
            ASM_VMCNT(2);  // drain current tile's 2 loads; next tile's stay in flight
        } else {
            ASM_VMCNT(0);
        }
        __builtin_amdgcn_sched_barrier(0);
        __builtin_amdgcn_s_barrier();
        __builtin_amdgcn_sched_barrier(0);

        const bool active = (k0 <= qw + 31);  // fully-masked tiles skip compute (barrier already hit)
        if (active) {
            // S = Q K^T  (pre-scaled: S already in log2 units)
            f4 sacc[2][4];
#pragma unroll
            for (int im = 0; im < 2; im++)
#pragma unroll
                for (int in = 0; in < 4; in++) sacc[im][in] = zz;
            __builtin_amdgcn_s_setprio(1);
#pragma unroll
            for (int kk = 0; kk < 2; kk++) {
                h8 kf[4];
#pragma unroll
                for (int in = 0; in < 4; in++) {
                    int row = in * 16 + (lane & 15);
                    int pc = (kk * 4 + (lane >> 4)) ^ (row & 7);
                    kf[in] = *(const h8*)(&lK[cur][0] + row * 64 + pc * 8);
                }
#pragma unroll
                for (int im = 0; im < 2; im++)
#pragma unroll
                    for (int in = 0; in < 4; in++)
                        sacc[im][in] = MFMA(qf[im][kk], kf[in], sacc[im][in]);
            }
            __builtin_amdgcn_s_setprio(0);

            const bool msk = (k0 + 63 > qw);
            if (msk) {
#pragma unroll
                for (int im = 0; im < 2; im++)
#pragma unroll
                    for (int in = 0; in < 4; in++)
#pragma unroll
                        for (int r = 0; r < 4; r++) {
                            int q = qw + im * 16 + (lane >> 4) * 4 + r;
                            int k = k0 + in * 16 + (lane & 15);
                            if (k > q) sacc[im][in][r] = -3e38f;
                        }
            }

#pragma unroll
            for (int im = 0; im < 2; im++) {
#pragma unroll
                for (int r = 0; r < 4; r++) {
                    float a0 = fmaxf(sacc[im][0][r], sacc[im][1][r]);
                    float a1 = fmaxf(sacc[im][2][r], sacc[im][3][r]);
                    float vmax4 = fmaxf(a0, a1);
                    if (!__all(vmax4 <= mrun[im][r] + 8.0f)) {
                        float vmax = rmax16(vmax4);
                        float mnew = fmaxf(mrun[im][r], vmax);
                        float sc = fexp2(mrun[im][r] - mnew);
                        lpart[im][r] *= sc;
#pragma unroll
                        for (int dn = 0; dn < 4; dn++) yacc[im][dn][r] *= sc;
                        mrun[im][r] = mnew;
                    }
                    float m = mrun[im][r];
                    float ls = 0.f;
#pragma unroll
                    for (int in = 0; in < 4; in++) {
                        float p = fexp2(sacc[im][in][r] - m);
                        sacc[im][in][r] = p;
                        ls += p;
                    }
                    lpart[im][r] += ls;
                }
            }

            // write P (f16) to per-wave swizzled LDS (same-wave round trip; no barrier)
#pragma unroll
            for (int im = 0; im < 2; im++)
#pragma unroll
                for (int in = 0; in < 4; in++)
#pragma unroll
                    for (int r = 0; r < 4; r++) {
                        int row = im * 16 + (lane >> 4) * 4 + r;
                        int col = in * 16 + (lane & 15);
                        lPw[row * 64 + (((col >> 3) ^ (row & 7)) * 8) + (col & 7)] =
                            (f16)sacc[im][in][r];
                    }

            // Y += P V   (V fragments direct from global; per-bh V panel is L2-resident)
            __builtin_amdgcn_s_setprio(1);
#pragma unroll
            for (int kk = 0; kk < 2; kk++) {
                h8 pf[2], vf[4];
#pragma unroll
                for (int dn = 0; dn < 4; dn++)
                    vf[dn] = *(const h8*)(Vb + (size_t)(dn * 16 + (lane & 15)) * 2048 + k0 +
                                          kk * 32 + (lane >> 4) * 8);
#pragma unroll
                for (int im = 0; im < 2; im++) {
                    int row = im * 16 + (lane & 15);
                    int pc = (kk * 4 + (lane >> 4)) ^ (row & 7);
                    pf[im] = *(const h8*)(lPw + row * 64 + pc * 8);
                }
#pragma unroll
                for (int im = 0; im < 2; im++)
#pragma unroll
                    for (int dn = 0; dn < 4; dn++)
                        yacc[im][dn] = MFMA(pf[im], vf[kk == 0 ? dn : dn], yacc[im][dn]);
            }
            __builtin_amdgcn_s_setprio(0);
        }
        cur = nxt;
    }

    const int b = bh >> 4, hh = bh & 15;
#pragma unroll
    for (int im = 0; im < 2; im++) {
#pragma unroll
        for (int r = 0; r < 4; r++) {
            float inv = 1.0f / rsum16(lpart[im][r]);
#pragma unroll
            for (int dn = 0; dn < 4; dn++) {
                int q = qw + im * 16 + (lane >> 4) * 4 + r;
                int d = dn * 16 + (lane & 15);
                O[((size_t)(b * 2048 + q)) * 1024 + hh * 64 + d] =
                    (f16)(yacc[im][dn][r] * inv);
            }
        }
    }
}

// ---------------- launch ----------------

extern "C" void kernel_launch(void* const* d_in, const int* in_sizes, int n_in,
                              void* d_out, int out_size, void* d_ws, size_t ws_size,
                              hipStream_t stream) {
    const float* x      = (const float*)d_in[0];
    const float* W_attn = (const float*)d_in[1];
    const float* b_attn = (const float*)d_in[2];
    const float* W_proj = (const float*)d_in[3];
    const float* b_proj = (const float*)d_in[4];
    float* out = (float*)d_out;

    char* ws = (char*)d_ws;
    f16* xb  = (f16*)ws;                                   // 16 MB (reused as attn out)
    f16* Wat = (f16*)(ws + 16777216);                      // 6 MB
    f16* Wpt = (f16*)(ws + 16777216 + 6291456);            // 2 MB
    f16* Vt  = (f16*)(ws + 16777216 + 6291456 + 2097152);  // 16 MB
    f16* Qs  = (f16*)d_out;                                // scratch: first 16 MB of out
    f16* Ks  = (f16*)((char*)d_out + 16777216);            // scratch: second 16 MB of out

    cvt_f16_kernel<<<4096, 256, 0, stream>>>(x, xb, 1048576);
    transpose_cvt<<<dim3(96, 32), dim3(32, 8), 0, stream>>>(W_attn, Wat, 1024, 3072);
    transpose_cvt<<<dim3(32, 32), dim3(32, 8), 0, stream>>>(W_proj, Wpt, 1024, 1024);
    qkv_gemm<<<1536, 256, 0, stream>>>(xb, Wat, b_attn, Qs, Ks, Vt);
    attn_kernel<<<1024, 256, 0, stream>>>(Qs, Ks, Vt, xb);
    proj_gemm<<<512, 256, 0, stream>>>(xb, Wpt, b_proj, out);
}

// Round 9
// 235.274 us; speedup vs baseline: 1.2885x; 1.0309x over previous
//
#include <hip/hip_runtime.h>

typedef _Float16 f16;
typedef __attribute__((ext_vector_type(8))) _Float16 h8;
typedef __attribute__((ext_vector_type(4))) _Float16 h4;
typedef __attribute__((ext_vector_type(4))) float f4;
typedef __attribute__((ext_vector_type(16))) float f16x;
typedef __attribute__((ext_vector_type(4))) unsigned u4;

#define MFMA(a, b, c) __builtin_amdgcn_mfma_f32_16x16x32_f16(a, b, c, 0, 0, 0)
#define MFMA32(a, b, c) __builtin_amdgcn_mfma_f32_32x32x16_f16(a, b, c, 0, 0, 0)

// Q prescale: 1/sqrt(64) * log2(e), folded into qkv epilogue -> softmax in base-2
#define QSCALE 0.18033688011112042f

__device__ __forceinline__ void gload16(const void* g, void* l) {
    __builtin_amdgcn_global_load_lds((const __attribute__((address_space(1))) void*)g,
                                     (__attribute__((address_space(3))) void*)l, 16, 0, 0);
}

__device__ __forceinline__ float fexp2(float x) {
    float r;
    asm("v_exp_f32 %0, %1" : "=v"(r) : "v"(x));
    return r;
}

// pack 2 f32 -> 2 f16 (RTZ) in one u32
__device__ __forceinline__ unsigned pkh(float a, float b) {
    auto r = __builtin_amdgcn_cvt_pkrtz(a, b);  // __fp16 ext_vector(2)
    return __builtin_bit_cast(unsigned, r);
}

// v_permlane32_swap_b32: a[l>=32] <-> b[l<32]  (both operands modified)
__device__ __forceinline__ void plswap(unsigned& a, unsigned& b) {
    asm volatile("v_permlane32_swap_b32 %0, %1" : "+v"(a), "+v"(b));
}

__device__ __forceinline__ float rsum16(float v) {
#pragma unroll
    for (int m = 1; m < 16; m <<= 1) v += __shfl_xor(v, m);
    return v;
}

// ---------------- conversion kernels ----------------

__global__ __launch_bounds__(256) void cvt_f16_kernel(const float* __restrict__ in,
                                                      f16* __restrict__ out, int n8) {
    int i = blockIdx.x * blockDim.x + threadIdx.x;
    if (i >= n8) return;
    const float4* p = (const float4*)in + (size_t)i * 2;
    float4 a = p[0], b = p[1];
    h8 o;
    o[0] = (f16)a.x; o[1] = (f16)a.y; o[2] = (f16)a.z; o[3] = (f16)a.w;
    o[4] = (f16)b.x; o[5] = (f16)b.y; o[6] = (f16)b.z; o[7] = (f16)b.w;
    *((h8*)out + i) = o;
}

// in: [R][Cc] f32 row-major -> out: [Cc][R] f16 row-major
__global__ __launch_bounds__(256) void transpose_cvt(const float* __restrict__ in,
                                                     f16* __restrict__ out, int R, int Cc) {
    __shared__ float tile[32][33];
    int tx = threadIdx.x, ty = threadIdx.y;
    int c0 = blockIdx.x * 32, r0 = blockIdx.y * 32;
#pragma unroll
    for (int k = 0; k < 32; k += 8)
        tile[ty + k][tx] = in[(size_t)(r0 + ty + k) * Cc + c0 + tx];
    __syncthreads();
#pragma unroll
    for (int k = 0; k < 32; k += 8)
        out[(size_t)(c0 + ty + k) * R + r0 + tx] = (f16)tile[tx][ty + k];
}

// ---------------- GEMM core (128x128 tile, BK=64, 4 waves, swizzled LDS) ----------------

__device__ __forceinline__ void gemm_core(const f16* __restrict__ A, const f16* __restrict__ Bt,
                                          int K, int m0, int n0,
                                          f16* lA, f16* lB, f4 acc[4][4]) {
    const int tid = threadIdx.x, lane = tid & 63, wave = tid >> 6;
    const int wm = (wave >> 1) * 64, wn = (wave & 1) * 64;
    for (int k0 = 0; k0 < K; k0 += 64) {
        __syncthreads();
#pragma unroll
        for (int i = 0; i < 4; i++) {
            int s = i * 256 + wave * 64 + lane;
            int row = s >> 3;
            int gc = ((s & 7) ^ (row & 7)) * 8;
            gload16(A + (size_t)(m0 + row) * K + k0 + gc, lA + (i * 256 + wave * 64) * 8);
        }
#pragma unroll
        for (int i = 0; i < 4; i++) {
            int s = i * 256 + wave * 64 + lane;
            int row = s >> 3;
            int gc = ((s & 7) ^ (row & 7)) * 8;
            gload16(Bt + (size_t)(n0 + row) * K + k0 + gc, lB + (i * 256 + wave * 64) * 8);
        }
        __syncthreads();
#pragma unroll
        for (int kk = 0; kk < 2; kk++) {
            h8 af[4], bg[4];
#pragma unroll
            for (int im = 0; im < 4; im++) {
                int row = wm + im * 16 + (lane & 15);
                int pc = (kk * 4 + (lane >> 4)) ^ (row & 7);
                af[im] = *(const h8*)(lA + row * 64 + pc * 8);
            }
#pragma unroll
            for (int in = 0; in < 4; in++) {
                int row = wn + in * 16 + (lane & 15);
                int pc = (kk * 4 + (lane >> 4)) ^ (row & 7);
                bg[in] = *(const h8*)(lB + row * 64 + pc * 8);
            }
#pragma unroll
            for (int im = 0; im < 4; im++)
#pragma unroll
                for (int in = 0; in < 4; in++)
                    acc[im][in] = MFMA(af[im], bg[in], acc[im][in]);
        }
    }
}

// ---------------- QKV GEMM: writes Q (prescaled), K [BH][T][64], V^T [BH][64][T] ----------------

__global__ __launch_bounds__(256) void qkv_gemm(const f16* __restrict__ A, const f16* __restrict__ Bt,
                                                const float* __restrict__ bias,
                                                f16* __restrict__ Qo, f16* __restrict__ Ko,
                                                f16* __restrict__ Vo) {
    __shared__ f16 lA[128 * 64], lB[128 * 64];
    f4 acc[4][4];
    const f4 zz = {0.f, 0.f, 0.f, 0.f};
#pragma unroll
    for (int i = 0; i < 4; i++)
#pragma unroll
        for (int j = 0; j < 4; j++) acc[i][j] = zz;

    const int swz = (blockIdx.x & 7) * 192 + (blockIdx.x >> 3);  // XCD-chunked (1536 = 8*192)
    const int nb = swz % 24, mb = swz / 24;
    gemm_core(A, Bt, 1024, mb * 128, nb * 128, lA, lB, acc);

    const int lane = threadIdx.x & 63, wave = threadIdx.x >> 6;
    const int wm = (wave >> 1) * 64, wn = (wave & 1) * 64;
#pragma unroll
    for (int im = 0; im < 4; im++) {
        int m4 = mb * 128 + wm + im * 16 + (lane >> 4) * 4;
        int b = m4 >> 11, t0 = m4 & 2047;
#pragma unroll
        for (int in = 0; in < 4; in++) {
            int n = nb * 128 + wn + in * 16 + (lane & 15);
            float bb = bias[n];
            int sec = n >> 10, cc = n & 1023, hh = cc >> 6, d = cc & 63;
            if (sec == 2) {
                h4 pv;
#pragma unroll
                for (int r = 0; r < 4; r++) pv[r] = (f16)(acc[im][in][r] + bb);
                *(h4*)(Vo + ((size_t)(b * 16 + hh) * 64 + d) * 2048 + t0) = pv;
            } else {
                f16* dst = sec ? Ko : Qo;
                float sc = sec ? 1.0f : QSCALE;  // Q prescaled for base-2 softmax
                size_t base = ((size_t)(b * 16 + hh) * 2048 + t0) * 64 + d;
#pragma unroll
                for (int r = 0; r < 4; r++)
                    dst[base + (size_t)r * 64] = (f16)((acc[im][in][r] + bb) * sc);
            }
        }
    }
}

// ---------------- Proj GEMM: f32 output + bias ----------------

__global__ __launch_bounds__(256) void proj_gemm(const f16* __restrict__ A, const f16* __restrict__ Bt,
                                                 const float* __restrict__ bias,
                                                 float* __restrict__ out) {
    __shared__ f16 lA[128 * 64], lB[128 * 64];
    f4 acc[4][4];
    const f4 zz = {0.f, 0.f, 0.f, 0.f};
#pragma unroll
    for (int i = 0; i < 4; i++)
#pragma unroll
        for (int j = 0; j < 4; j++) acc[i][j] = zz;

    const int swz = (blockIdx.x & 7) * 64 + (blockIdx.x >> 3);  // XCD-chunked (512 = 8*64)
    const int nb = swz & 7, mb = swz >> 3;
    gemm_core(A, Bt, 1024, mb * 128, nb * 128, lA, lB, acc);

    const int lane = threadIdx.x & 63, wave = threadIdx.x >> 6;
    const int wm = (wave >> 1) * 64, wn = (wave & 1) * 64;
#pragma unroll
    for (int im = 0; im < 4; im++) {
        int m4 = mb * 128 + wm + im * 16 + (lane >> 4) * 4;
#pragma unroll
        for (int in = 0; in < 4; in++) {
            int n = nb * 128 + wn + in * 16 + (lane & 15);
            float bb = bias[n];
#pragma unroll
            for (int r = 0; r < 4; r++)
                out[(size_t)(m4 + r) * 1024 + n] = acc[im][in][r] + bb;
        }
    }
}

// ---------------- Flash attention (swapped QK^T, in-register softmax/P, no P-LDS) ----------------
// Q(prescaled),K: [BH][2048][64] f16; Vg: [BH][64][2048] f16 (transposed); O: [B][2048][1024] f16
// Grid 1024: 1 block = 128 q-rows; 4 waves x 32 rows; KV tiles of 64; balance permutation.
// K triple-buffered LDS, counted vmcnt(2), ONE barrier/tile (R7 structure).
// QK^T computed SWAPPED via mfma_32x32x16: S^T = K.Q^T -> lane owns q = lane&31;
// softmax register-local (one shfl_xor(32)); P->A-operand via cvt_pkrtz + permlane32_swap.
// Layouts (32x32x16): A: row=lane&31, k=(lane>>5)*8+e; B: col=lane&31, k=(lane>>5)*8+e;
// C/D: col=lane&31, row=crow(r,hi)=(r&3)+8*(r>>2)+4*hi  [m74/m101].

#define ASM_VMCNT(N) asm volatile("s_waitcnt vmcnt(" #N ")" ::: "memory")

__global__ __launch_bounds__(256) void attn_kernel(const f16* __restrict__ Q, const f16* __restrict__ K,
                                                   const f16* __restrict__ Vg, f16* __restrict__ O) {
    __shared__ f16 lK[3][64 * 64];
    const int tid = threadIdx.x, lane = tid & 63, wave = tid >> 6;
    const int hi = lane >> 5, ln = lane & 31;
    const int bh = blockIdx.x & 63;
    const int g = blockIdx.x >> 6;
    const int qb = (int)((0x75318ACE64209BDFull >> (g * 4)) & 15);
    const int q0 = qb * 128;
    const int qw = q0 + wave * 32;
    const f16* Qb = Q + (size_t)bh * 2048 * 64;
    const f16* Kb = K + (size_t)bh * 2048 * 64;
    const f16* Vb = Vg + (size_t)bh * 64 * 2048;

    // hoist Q fragments (B-operand): Q[qw+ln][dd*16 + hi*8 .. +8]
    h8 qf[4];
#pragma unroll
    for (int dd = 0; dd < 4; dd++)
        qf[dd] = *(const h8*)(Qb + (size_t)(qw + ln) * 64 + dd * 16 + hi * 8);

    float mrun = -3e38f, lpart = 0.f;
    f16x y0, y1;
#pragma unroll
    for (int r = 0; r < 16; r++) { y0[r] = 0.f; y1[r] = 0.f; }

    const int nt = q0 / 64 + 2;

    // prologue: stage K tile 0 into buffer 0
#pragma unroll
    for (int i = 0; i < 2; i++) {
        int s = i * 256 + wave * 64 + lane;
        int row = s >> 3;
        int gc = ((s & 7) ^ (row & 7)) * 8;
        gload16(Kb + (size_t)row * 64 + gc, &lK[0][(i * 256 + wave * 64) * 8]);
    }

    int cur = 0;
    for (int it = 0; it < nt; it++) {
        const int k0 = it * 64;
        int nxt = cur + 1;
        if (nxt == 3) nxt = 0;

        if (it + 1 < nt) {
#pragma unroll
            for (int i = 0; i < 2; i++) {
                int s = i * 256 + wave * 64 + lane;
                int row = s >> 3;
                int gc = ((s & 7) ^ (row & 7)) * 8;
                gload16(Kb + (size_t)(k0 + 64 + row) * 64 + gc,
                        &lK[nxt][(i * 256 + wave * 64) * 8]);
            }
            ASM_VMCNT(2);  // drain current tile's 2 loads; next tile's stay in flight
        } else {
            ASM_VMCNT(0);
        }
        __builtin_amdgcn_sched_barrier(0);
        __builtin_amdgcn_s_barrier();
        __builtin_amdgcn_sched_barrier(0);

        const bool active = (k0 <= qw + 31);
        if (active) {
            // S^T = K.Q^T  (A = K rows, B = Q rows); s0: k in [k0,k0+32), s1: [k0+32,k0+64)
            f16x s0, s1;
#pragma unroll
            for (int r = 0; r < 16; r++) { s0[r] = 0.f; s1[r] = 0.f; }
            __builtin_amdgcn_s_setprio(1);
#pragma unroll
            for (int dd = 0; dd < 4; dd++) {
                const int c = (dd * 2 + hi) ^ (ln & 7);  // swizzled 16B-chunk index
                h8 ka = *(const h8*)(&lK[cur][0] + ln * 64 + c * 8);
                h8 kb = *(const h8*)(&lK[cur][0] + (32 + ln) * 64 + c * 8);
                s0 = MFMA32(ka, qf[dd], s0);
                s1 = MFMA32(kb, qf[dd], s1);
            }
            __builtin_amdgcn_s_setprio(0);

            const int qg = qw + ln;  // this lane's q row
            if (k0 + 63 > qw) {      // diagonal tile: causal mask
#pragma unroll
                for (int r = 0; r < 16; r++) {
                    int kl = (r & 3) + 8 * (r >> 2) + 4 * hi;
                    if (k0 + kl > qg) s0[r] = -3e38f;
                    if (k0 + 32 + kl > qg) s1[r] = -3e38f;
                }
            }

            // register-local softmax (base-2, defer-max)
            float vmax = s0[0];
#pragma unroll
            for (int r = 1; r < 16; r++) vmax = fmaxf(vmax, s0[r]);
#pragma unroll
            for (int r = 0; r < 16; r++) vmax = fmaxf(vmax, s1[r]);
            vmax = fmaxf(vmax, __shfl_xor(vmax, 32));
            if (!__all(vmax <= mrun + 8.0f)) {
                float mnew = fmaxf(mrun, vmax);
                float sc = fexp2(mrun - mnew);
                lpart *= sc;
                mrun = mnew;
#pragma unroll
                for (int r = 0; r < 16; r++) {
                    float scy = __shfl(sc, (r & 3) + 8 * (r >> 2) + 4 * hi);
                    y0[r] *= scy;
                    y1[r] *= scy;
                }
            }
            float ls = 0.f;
#pragma unroll
            for (int r = 0; r < 16; r++) {
                float p0 = fexp2(s0[r] - mrun);
                float p1 = fexp2(s1[r] - mrun);
                s0[r] = p0; s1[r] = p1;
                ls += p0 + p1;
            }
            lpart += ls;

            // P -> PV A-fragments: 16 cvt_pk + 8 permlane32_swap (no LDS)
            h8 pa[4];
            {
                unsigned a0 = pkh(s0[0], s0[1]), a1 = pkh(s0[2], s0[3]);
                unsigned b0 = pkh(s0[4], s0[5]), b1 = pkh(s0[6], s0[7]);
                plswap(a0, b0); plswap(a1, b1);
                u4 w0; w0[0] = a0; w0[1] = a1; w0[2] = b0; w0[3] = b1;
                pa[0] = __builtin_bit_cast(h8, w0);
                unsigned c0 = pkh(s0[8], s0[9]), c1 = pkh(s0[10], s0[11]);
                unsigned d0 = pkh(s0[12], s0[13]), d1 = pkh(s0[14], s0[15]);
                plswap(c0, d0); plswap(c1, d1);
                u4 w1; w1[0] = c0; w1[1] = c1; w1[2] = d0; w1[3] = d1;
                pa[1] = __builtin_bit_cast(h8, w1);
                unsigned e0 = pkh(s1[0], s1[1]), e1 = pkh(s1[2], s1[3]);
                unsigned f0 = pkh(s1[4], s1[5]), f1 = pkh(s1[6], s1[7]);
                plswap(e0, f0); plswap(e1, f1);
                u4 w2; w2[0] = e0; w2[1] = e1; w2[2] = f0; w2[3] = f1;
                pa[2] = __builtin_bit_cast(h8, w2);
                unsigned g0 = pkh(s1[8], s1[9]), g1 = pkh(s1[10], s1[11]);
                unsigned h0 = pkh(s1[12], s1[13]), h1 = pkh(s1[14], s1[15]);
                plswap(g0, h0); plswap(g1, h1);
                u4 w3; w3[0] = g0; w3[1] = g1; w3[2] = h0; w3[3] = h1;
                pa[3] = __builtin_bit_cast(h8, w3);
            }

            // Y += P V  (V B-fragments direct from global V^T; per-bh panel L2-resident)
            __builtin_amdgcn_s_setprio(1);
#pragma unroll
            for (int ks = 0; ks < 4; ks++) {
                h8 v0 = *(const h8*)(Vb + (size_t)ln * 2048 + k0 + ks * 16 + hi * 8);
                h8 v1 = *(const h8*)(Vb + (size_t)(32 + ln) * 2048 + k0 + ks * 16 + hi * 8);
                y0 = MFMA32(pa[ks], v0, y0);
                y1 = MFMA32(pa[ks], v1, y1);
            }
            __builtin_amdgcn_s_setprio(0);
        }
        cur = nxt;
    }

    // epilogue: combine half-lane partials, normalize, store
    const int b = bh >> 4, hh = bh & 15;
    float lT = lpart + __shfl_xor(lpart, 32);
    float inv = 1.0f / lT;
#pragma unroll
    for (int r = 0; r < 16; r++) {
        int crow = (r & 3) + 8 * (r >> 2) + 4 * hi;
        float invr = __shfl(inv, crow);
        size_t base = ((size_t)(b * 2048 + qw + crow)) * 1024 + hh * 64 + ln;
        O[base] = (f16)(y0[r] * invr);
        O[base + 32] = (f16)(y1[r] * invr);
    }
}

// ---------------- launch ----------------

extern "C" void kernel_launch(void* const* d_in, const int* in_sizes, int n_in,
                              void* d_out, int out_size, void* d_ws, size_t ws_size,
                              hipStream_t stream) {
    const float* x      = (const float*)d_in[0];
    const float* W_attn = (const float*)d_in[1];
    const float* b_attn = (const float*)d_in[2];
    const float* W_proj = (const float*)d_in[3];
    const float* b_proj = (const float*)d_in[4];
    float* out = (float*)d_out;

    char* ws = (char*)d_ws;
    f16* xb  = (f16*)ws;                                   // 16 MB (reused as attn out)
    f16* Wat = (f16*)(ws + 16777216);                      // 6 MB
    f16* Wpt = (f16*)(ws + 16777216 + 6291456);            // 2 MB
    f16* Vt  = (f16*)(ws + 16777216 + 6291456 + 2097152);  // 16 MB
    f16* Qs  = (f16*)d_out;                                // scratch: first 16 MB of out
    f16* Ks  = (f16*)((char*)d_out + 16777216);            // scratch: second 16 MB of out

    cvt_f16_kernel<<<4096, 256, 0, stream>>>(x, xb, 1048576);
    transpose_cvt<<<dim3(96, 32), dim3(32, 8), 0, stream>>>(W_attn, Wat, 1024, 3072);
    transpose_cvt<<<dim3(32, 32), dim3(32, 8), 0, stream>>>(W_proj, Wpt, 1024, 1024);
    qkv_gemm<<<1536, 256, 0, stream>>>(xb, Wat, b_attn, Qs, Ks, Vt);
    attn_kernel<<<1024, 256, 0, stream>>>(Qs, Ks, Vt, xb);
    proj_gemm<<<512, 256, 0, stream>>>(xb, Wpt, b_proj, out);
}

// Round 10
// 219.452 us; speedup vs baseline: 1.3814x; 1.0721x over previous
//
#include <hip/hip_runtime.h>

typedef _Float16 f16;
typedef __attribute__((ext_vector_type(8))) _Float16 h8;
typedef __attribute__((ext_vector_type(4))) _Float16 h4;
typedef __attribute__((ext_vector_type(4))) float f4;
typedef __attribute__((ext_vector_type(16))) float f16x;
typedef __attribute__((ext_vector_type(4))) unsigned u4;

#define MFMA(a, b, c) __builtin_amdgcn_mfma_f32_16x16x32_f16(a, b, c, 0, 0, 0)
#define MFMA32(a, b, c) __builtin_amdgcn_mfma_f32_32x32x16_f16(a, b, c, 0, 0, 0)

// Q prescale: 1/sqrt(64) * log2(e), folded into qkv epilogue -> softmax in base-2
#define QSCALE 0.18033688011112042f

__device__ __forceinline__ void gload16(const void* g, void* l) {
    __builtin_amdgcn_global_load_lds((const __attribute__((address_space(1))) void*)g,
                                     (__attribute__((address_space(3))) void*)l, 16, 0, 0);
}

__device__ __forceinline__ float fexp2(float x) {
    float r;
    asm("v_exp_f32 %0, %1" : "=v"(r) : "v"(x));
    return r;
}

// pack 2 f32 -> 2 f16 (RTZ) in one u32
__device__ __forceinline__ unsigned pkh(float a, float b) {
    auto r = __builtin_amdgcn_cvt_pkrtz(a, b);  // __fp16 ext_vector(2)
    return __builtin_bit_cast(unsigned, r);
}

// v_permlane32_swap_b32: a[l>=32] <-> b[l<32]  (both operands modified)
__device__ __forceinline__ void plswap(unsigned& a, unsigned& b) {
    asm volatile("v_permlane32_swap_b32 %0, %1" : "+v"(a), "+v"(b));
}

// ---------------- conversion kernels ----------------

__global__ __launch_bounds__(256) void cvt_f16_kernel(const float* __restrict__ in,
                                                      f16* __restrict__ out, int n8) {
    int i = blockIdx.x * blockDim.x + threadIdx.x;
    if (i >= n8) return;
    const float4* p = (const float4*)in + (size_t)i * 2;
    float4 a = p[0], b = p[1];
    h8 o;
    o[0] = (f16)a.x; o[1] = (f16)a.y; o[2] = (f16)a.z; o[3] = (f16)a.w;
    o[4] = (f16)b.x; o[5] = (f16)b.y; o[6] = (f16)b.z; o[7] = (f16)b.w;
    *((h8*)out + i) = o;
}

// in: [R][Cc] f32 row-major -> out: [Cc][R] f16 row-major
__global__ __launch_bounds__(256) void transpose_cvt(const float* __restrict__ in,
                                                     f16* __restrict__ out, int R, int Cc) {
    __shared__ float tile[32][33];
    int tx = threadIdx.x, ty = threadIdx.y;
    int c0 = blockIdx.x * 32, r0 = blockIdx.y * 32;
#pragma unroll
    for (int k = 0; k < 32; k += 8)
        tile[ty + k][tx] = in[(size_t)(r0 + ty + k) * Cc + c0 + tx];
    __syncthreads();
#pragma unroll
    for (int k = 0; k < 32; k += 8)
        out[(size_t)(c0 + ty + k) * R + r0 + tx] = (f16)tile[tx][ty + k];
}

// ---------------- GEMM core (128x128 tile, BK=64, 4 waves, swizzled LDS) ----------------

__device__ __forceinline__ void gemm_core(const f16* __restrict__ A, const f16* __restrict__ Bt,
                                          int K, int m0, int n0,
                                          f16* lA, f16* lB, f4 acc[4][4]) {
    const int tid = threadIdx.x, lane = tid & 63, wave = tid >> 6;
    const int wm = (wave >> 1) * 64, wn = (wave & 1) * 64;
    for (int k0 = 0; k0 < K; k0 += 64) {
        __syncthreads();
#pragma unroll
        for (int i = 0; i < 4; i++) {
            int s = i * 256 + wave * 64 + lane;
            int row = s >> 3;
            int gc = ((s & 7) ^ (row & 7)) * 8;
            gload16(A + (size_t)(m0 + row) * K + k0 + gc, lA + (i * 256 + wave * 64) * 8);
        }
#pragma unroll
        for (int i = 0; i < 4; i++) {
            int s = i * 256 + wave * 64 + lane;
            int row = s >> 3;
            int gc = ((s & 7) ^ (row & 7)) * 8;
            gload16(Bt + (size_t)(n0 + row) * K + k0 + gc, lB + (i * 256 + wave * 64) * 8);
        }
        __syncthreads();
#pragma unroll
        for (int kk = 0; kk < 2; kk++) {
            h8 af[4], bg[4];
#pragma unroll
            for (int im = 0; im < 4; im++) {
                int row = wm + im * 16 + (lane & 15);
                int pc = (kk * 4 + (lane >> 4)) ^ (row & 7);
                af[im] = *(const h8*)(lA + row * 64 + pc * 8);
            }
#pragma unroll
            for (int in = 0; in < 4; in++) {
                int row = wn + in * 16 + (lane & 15);
                int pc = (kk * 4 + (lane >> 4)) ^ (row & 7);
                bg[in] = *(const h8*)(lB + row * 64 + pc * 8);
            }
#pragma unroll
            for (int im = 0; im < 4; im++)
#pragma unroll
                for (int in = 0; in < 4; in++)
                    acc[im][in] = MFMA(af[im], bg[in], acc[im][in]);
        }
    }
}

// ---------------- QKV GEMM: writes Q (prescaled), K [BH][T][64], V^T [BH][64][T] ----------------

__global__ __launch_bounds__(256) void qkv_gemm(const f16* __restrict__ A, const f16* __restrict__ Bt,
                                                const float* __restrict__ bias,
                                                f16* __restrict__ Qo, f16* __restrict__ Ko,
                                                f16* __restrict__ Vo) {
    __shared__ f16 lA[128 * 64], lB[128 * 64];
    f4 acc[4][4];
    const f4 zz = {0.f, 0.f, 0.f, 0.f};
#pragma unroll
    for (int i = 0; i < 4; i++)
#pragma unroll
        for (int j = 0; j < 4; j++) acc[i][j] = zz;

    const int swz = (blockIdx.x & 7) * 192 + (blockIdx.x >> 3);  // XCD-chunked (1536 = 8*192)
    const int nb = swz % 24, mb = swz / 24;
    gemm_core(A, Bt, 1024, mb * 128, nb * 128, lA, lB, acc);

    const int lane = threadIdx.x & 63, wave = threadIdx.x >> 6;
    const int wm = (wave >> 1) * 64, wn = (wave & 1) * 64;
#pragma unroll
    for (int im = 0; im < 4; im++) {
        int m4 = mb * 128 + wm + im * 16 + (lane >> 4) * 4;
        int b = m4 >> 11, t0 = m4 & 2047;
#pragma unroll
        for (int in = 0; in < 4; in++) {
            int n = nb * 128 + wn + in * 16 + (lane & 15);
            float bb = bias[n];
            int sec = n >> 10, cc = n & 1023, hh = cc >> 6, d = cc & 63;
            if (sec == 2) {
                h4 pv;
#pragma unroll
                for (int r = 0; r < 4; r++) pv[r] = (f16)(acc[im][in][r] + bb);
                *(h4*)(Vo + ((size_t)(b * 16 + hh) * 64 + d) * 2048 + t0) = pv;
            } else {
                f16* dst = sec ? Ko : Qo;
                float sc = sec ? 1.0f : QSCALE;  // Q prescaled for base-2 softmax
                size_t base = ((size_t)(b * 16 + hh) * 2048 + t0) * 64 + d;
#pragma unroll
                for (int r = 0; r < 4; r++)
                    dst[base + (size_t)r * 64] = (f16)((acc[im][in][r] + bb) * sc);
            }
        }
    }
}

// ---------------- Proj GEMM: f32 output + bias ----------------

__global__ __launch_bounds__(256) void proj_gemm(const f16* __restrict__ A, const f16* __restrict__ Bt,
                                                 const float* __restrict__ bias,
                                                 float* __restrict__ out) {
    __shared__ f16 lA[128 * 64], lB[128 * 64];
    f4 acc[4][4];
    const f4 zz = {0.f, 0.f, 0.f, 0.f};
#pragma unroll
    for (int i = 0; i < 4; i++)
#pragma unroll
        for (int j = 0; j < 4; j++) acc[i][j] = zz;

    const int swz = (blockIdx.x & 7) * 64 + (blockIdx.x >> 3);  // XCD-chunked (512 = 8*64)
    const int nb = swz & 7, mb = swz >> 3;
    gemm_core(A, Bt, 1024, mb * 128, nb * 128, lA, lB, acc);

    const int lane = threadIdx.x & 63, wave = threadIdx.x >> 6;
    const int wm = (wave >> 1) * 64, wn = (wave & 1) * 64;
#pragma unroll
    for (int im = 0; im < 4; im++) {
        int m4 = mb * 128 + wm + im * 16 + (lane >> 4) * 4;
#pragma unroll
        for (int in = 0; in < 4; in++) {
            int n = nb * 128 + wn + in * 16 + (lane & 15);
            float bb = bias[n];
#pragma unroll
            for (int r = 0; r < 4; r++)
                out[(size_t)(m4 + r) * 1024 + n] = acc[im][in][r] + bb;
        }
    }
}

// ---------------- Flash attention: WAVE-INDEPENDENT, zero barriers ----------------
// Q(prescaled),K: [BH][2048][64] f16; Vg: [BH][64][2048] f16 (transposed); O: [B][2048][1024] f16
// Grid 1024: 1 block = 128 q-rows; 4 waves x 32 rows; balance permutation at block level.
// Each wave: PRIVATE double-buffered LDS K-stage (KVBLK=32, 2x4KB), global_load_lds +
// per-wave vmcnt(4) -> no s_barrier anywhere, waves fully decoupled.
// Swapped QK^T (S^T = K.Q^T, mfma_32x32x16), in-register softmax (base-2, defer-max),
// P->A via cvt_pkrtz + permlane32_swap (layout HW-verified in R9).
// Last tile (k0 == qw) is the only masked one: mask is simply (kl > ln).

#define ASM_VMCNT(N) asm volatile("s_waitcnt vmcnt(" #N ")" ::: "memory")

__global__ __launch_bounds__(256) void attn_kernel(const f16* __restrict__ Q, const f16* __restrict__ K,
                                                   const f16* __restrict__ Vg, f16* __restrict__ O) {
    __shared__ f16 lK[4 * 2 * 2048];  // [wave][buf][32 rows x 64]
    const int tid = threadIdx.x, lane = tid & 63, wave = tid >> 6;
    const int hi = lane >> 5, ln = lane & 31;
    const int bh = blockIdx.x & 63;
    const int g = blockIdx.x >> 6;
    const int qb = (int)((0x75318ACE64209BDFull >> (g * 4)) & 15);
    const int q0 = qb * 128;
    const int qw = q0 + wave * 32;
    const f16* Qb = Q + (size_t)bh * 2048 * 64;
    const f16* Kb = K + (size_t)bh * 2048 * 64;
    const f16* Vb = Vg + (size_t)bh * 64 * 2048;
    f16* myK = lK + wave * 4096;  // my two 4KB buffers

    // hoist Q fragments (B-operand): Q[qw+ln][dd*16 + hi*8 .. +8]
    h8 qf[4];
#pragma unroll
    for (int dd = 0; dd < 4; dd++)
        qf[dd] = *(const h8*)(Qb + (size_t)(qw + ln) * 64 + dd * 16 + hi * 8);

    float mrun = -3e38f, lpart = 0.f;
    f16x y0, y1;
#pragma unroll
    for (int r = 0; r < 16; r++) { y0[r] = 0.f; y1[r] = 0.f; }

    const int nt = (qw >> 5) + 1;  // per-wave tile count (KVBLK=32); last tile k0 == qw

    // prologue: this wave stages its tile 0 into buf 0 (4 x gload16 = 4KB)
#pragma unroll
    for (int i = 0; i < 4; i++) {
        int s = i * 64 + lane;
        int row = s >> 3;
        int gc = ((s & 7) ^ (row & 7)) * 8;
        gload16(Kb + (size_t)row * 64 + gc, myK + i * 512);
    }

    for (int it = 0; it < nt; it++) {
        const int k0 = it * 32;
        const int cb = (it & 1) * 2048, nb2 = ((it + 1) & 1) * 2048;

        if (it + 1 < nt) {
            // stage next tile into other private buffer; loads stay in flight
#pragma unroll
            for (int i = 0; i < 4; i++) {
                int s = i * 64 + lane;
                int row = s >> 3;
                int gc = ((s & 7) ^ (row & 7)) * 8;
                gload16(Kb + (size_t)(k0 + 32 + row) * 64 + gc, myK + nb2 + i * 512);
            }
            ASM_VMCNT(4);  // wait only this wave's current-tile 4 loads
        } else {
            ASM_VMCNT(0);
        }
        __builtin_amdgcn_sched_barrier(0);

        // V fragment loads issued EARLY (consumed at PV; QK+softmax hides L2 latency)
        h8 vf[2][2];
#pragma unroll
        for (int ks = 0; ks < 2; ks++)
#pragma unroll
            for (int j = 0; j < 2; j++)
                vf[ks][j] = *(const h8*)(Vb + (size_t)(j * 32 + ln) * 2048 + k0 + ks * 16 + hi * 8);

        // S^T = K.Q^T (A = K rows from private LDS, B = Q regs); lane owns q = qw+ln
        f16x s0;
#pragma unroll
        for (int r = 0; r < 16; r++) s0[r] = 0.f;
        __builtin_amdgcn_s_setprio(1);
#pragma unroll
        for (int dd = 0; dd < 4; dd++) {
            const int c = (dd * 2 + hi) ^ (ln & 7);  // swizzled 16B-chunk index
            h8 ka = *(const h8*)(myK + cb + ln * 64 + c * 8);
            s0 = MFMA32(ka, qf[dd], s0);
        }
        __builtin_amdgcn_s_setprio(0);

        if (it == nt - 1) {  // diagonal tile (k0 == qw): mask k-local kl > ln
#pragma unroll
            for (int r = 0; r < 16; r++) {
                int kl = (r & 3) + 8 * (r >> 2) + 4 * hi;
                if (kl > ln) s0[r] = -3e38f;
            }
        }

        // register-local softmax (base-2, defer-max)
        float vmax = s0[0];
#pragma unroll
        for (int r = 1; r < 16; r++) vmax = fmaxf(vmax, s0[r]);
        vmax = fmaxf(vmax, __shfl_xor(vmax, 32));
        if (!__all(vmax <= mrun + 8.0f)) {
            float mnew = fmaxf(mrun, vmax);
            float sc = fexp2(mrun - mnew);
            lpart *= sc;
            mrun = mnew;
#pragma unroll
            for (int r = 0; r < 16; r++) {
                float scy = __shfl(sc, (r & 3) + 8 * (r >> 2) + 4 * hi);
                y0[r] *= scy;
                y1[r] *= scy;
            }
        }
        float ls = 0.f;
#pragma unroll
        for (int r = 0; r < 16; r++) {
            float p = fexp2(s0[r] - mrun);
            s0[r] = p;
            ls += p;
        }
        lpart += ls;

        // P -> PV A-fragments: 8 cvt_pk + 4 permlane32_swap (no LDS; verified in R9)
        h8 pa[2];
        {
            unsigned a0 = pkh(s0[0], s0[1]), a1 = pkh(s0[2], s0[3]);
            unsigned b0 = pkh(s0[4], s0[5]), b1 = pkh(s0[6], s0[7]);
            plswap(a0, b0); plswap(a1, b1);
            u4 w0; w0[0] = a0; w0[1] = a1; w0[2] = b0; w0[3] = b1;
            pa[0] = __builtin_bit_cast(h8, w0);
            unsigned c0 = pkh(s0[8], s0[9]), c1 = pkh(s0[10], s0[11]);
            unsigned d0 = pkh(s0[12], s0[13]), d1 = pkh(s0[14], s0[15]);
            plswap(c0, d0); plswap(c1, d1);
            u4 w1; w1[0] = c0; w1[1] = c1; w1[2] = d0; w1[3] = d1;
            pa[1] = __builtin_bit_cast(h8, w1);
        }

        // Y += P V
        __builtin_amdgcn_s_setprio(1);
#pragma unroll
        for (int ks = 0; ks < 2; ks++) {
            y0 = MFMA32(pa[ks], vf[ks][0], y0);
            y1 = MFMA32(pa[ks], vf[ks][1], y1);
        }
        __builtin_amdgcn_s_setprio(0);
    }

    // epilogue: combine half-lane partials, normalize, store
    const int b = bh >> 4, hh = bh & 15;
    float lT = lpart + __shfl_xor(lpart, 32);
    float inv = 1.0f / lT;
#pragma unroll
    for (int r = 0; r < 16; r++) {
        int crow = (r & 3) + 8 * (r >> 2) + 4 * hi;
        float invr = __shfl(inv, crow);
        size_t base = ((size_t)(b * 2048 + qw + crow)) * 1024 + hh * 64 + ln;
        O[base] = (f16)(y0[r] * invr);
        O[base + 32] = (f16)(y1[r] * invr);
    }
}

// ---------------- launch ----------------

extern "C" void kernel_launch(void* const* d_in, const int* in_sizes, int n_in,
                              void* d_out, int out_size, void* d_ws, size_t ws_size,
                              hipStream_t stream) {
    const float* x      = (const float*)d_in[0];
    const float* W_attn = (const float*)d_in[1];
    const float* b_attn = (const float*)d_in[2];
    const float* W_proj = (const float*)d_in[3];
    const float* b_proj = (const float*)d_in[4];
    float* out = (float*)d_out;

    char* ws = (char*)d_ws;
    f16* xb  = (f16*)ws;                                   // 16 MB (reused as attn out)
    f16* Wat = (f16*)(ws + 16777216);                      // 6 MB
    f16* Wpt = (f16*)(ws + 16777216 + 6291456);            // 2 MB
    f16* Vt  = (f16*)(ws + 16777216 + 6291456 + 2097152);  // 16 MB
    f16* Qs  = (f16*)d_out;                                // scratch: first 16 MB of out
    f16* Ks  = (f16*)((char*)d_out + 16777216);            // scratch: second 16 MB of out

    cvt_f16_kernel<<<4096, 256, 0, stream>>>(x, xb, 1048576);
    transpose_cvt<<<dim3(96, 32), dim3(32, 8), 0, stream>>>(W_attn, Wat, 1024, 3072);
    transpose_cvt<<<dim3(32, 32), dim3(32, 8), 0, stream>>>(W_proj, Wpt, 1024, 1024);
    qkv_gemm<<<1536, 256, 0, stream>>>(xb, Wat, b_attn, Qs, Ks, Vt);
    attn_kernel<<<1024, 256, 0, stream>>>(Qs, Ks, Vt, xb);
    proj_gemm<<<512, 256, 0, stream>>>(xb, Wpt, b_proj, out);
}

// Round 11
// 206.600 us; speedup vs baseline: 1.4673x; 1.0622x over previous
//
#include <hip/hip_runtime.h>

typedef _Float16 f16;
typedef __attribute__((ext_vector_type(8))) _Float16 h8;
typedef __attribute__((ext_vector_type(4))) _Float16 h4;
typedef __attribute__((ext_vector_type(4))) float f4;
typedef __attribute__((ext_vector_type(16))) float f16x;
typedef __attribute__((ext_vector_type(4))) unsigned u4;

#define MFMA(a, b, c) __builtin_amdgcn_mfma_f32_16x16x32_f16(a, b, c, 0, 0, 0)
#define MFMA32(a, b, c) __builtin_amdgcn_mfma_f32_32x32x16_f16(a, b, c, 0, 0, 0)

// Q prescale: 1/sqrt(64) * log2(e), folded into qkv epilogue -> softmax in base-2
#define QSCALE 0.18033688011112042f

__device__ __forceinline__ void gload16(const void* g, void* l) {
    __builtin_amdgcn_global_load_lds((const __attribute__((address_space(1))) void*)g,
                                     (__attribute__((address_space(3))) void*)l, 16, 0, 0);
}

__device__ __forceinline__ float fexp2(float x) {
    float r;
    asm("v_exp_f32 %0, %1" : "=v"(r) : "v"(x));
    return r;
}

// pack 2 f32 -> 2 f16 (RTZ) in one u32
__device__ __forceinline__ unsigned pkh(float a, float b) {
    auto r = __builtin_amdgcn_cvt_pkrtz(a, b);  // __fp16 ext_vector(2)
    return __builtin_bit_cast(unsigned, r);
}

// v_permlane32_swap_b32: a[l>=32] <-> b[l<32]  (both operands modified)
__device__ __forceinline__ void plswap(unsigned& a, unsigned& b) {
    asm volatile("v_permlane32_swap_b32 %0, %1" : "+v"(a), "+v"(b));
}

// ---------------- conversion kernels ----------------

__global__ __launch_bounds__(256) void cvt_f16_kernel(const float* __restrict__ in,
                                                      f16* __restrict__ out, int n8) {
    int i = blockIdx.x * blockDim.x + threadIdx.x;
    if (i >= n8) return;
    const float4* p = (const float4*)in + (size_t)i * 2;
    float4 a = p[0], b = p[1];
    h8 o;
    o[0] = (f16)a.x; o[1] = (f16)a.y; o[2] = (f16)a.z; o[3] = (f16)a.w;
    o[4] = (f16)b.x; o[5] = (f16)b.y; o[6] = (f16)b.z; o[7] = (f16)b.w;
    *((h8*)out + i) = o;
}

// in: [R][Cc] f32 row-major -> out: [Cc][R] f16 row-major
__global__ __launch_bounds__(256) void transpose_cvt(const float* __restrict__ in,
                                                     f16* __restrict__ out, int R, int Cc) {
    __shared__ float tile[32][33];
    int tx = threadIdx.x, ty = threadIdx.y;
    int c0 = blockIdx.x * 32, r0 = blockIdx.y * 32;
#pragma unroll
    for (int k = 0; k < 32; k += 8)
        tile[ty + k][tx] = in[(size_t)(r0 + ty + k) * Cc + c0 + tx];
    __syncthreads();
#pragma unroll
    for (int k = 0; k < 32; k += 8)
        out[(size_t)(c0 + ty + k) * R + r0 + tx] = (f16)tile[tx][ty + k];
}

// ---------------- GEMM core (128x128 tile, BK=64, 4 waves, swizzled LDS) ----------------

__device__ __forceinline__ void gemm_core(const f16* __restrict__ A, const f16* __restrict__ Bt,
                                          int K, int m0, int n0,
                                          f16* lA, f16* lB, f4 acc[4][4]) {
    const int tid = threadIdx.x, lane = tid & 63, wave = tid >> 6;
    const int wm = (wave >> 1) * 64, wn = (wave & 1) * 64;
    for (int k0 = 0; k0 < K; k0 += 64) {
        __syncthreads();
#pragma unroll
        for (int i = 0; i < 4; i++) {
            int s = i * 256 + wave * 64 + lane;
            int row = s >> 3;
            int gc = ((s & 7) ^ (row & 7)) * 8;
            gload16(A + (size_t)(m0 + row) * K + k0 + gc, lA + (i * 256 + wave * 64) * 8);
        }
#pragma unroll
        for (int i = 0; i < 4; i++) {
            int s = i * 256 + wave * 64 + lane;
            int row = s >> 3;
            int gc = ((s & 7) ^ (row & 7)) * 8;
            gload16(Bt + (size_t)(n0 + row) * K + k0 + gc, lB + (i * 256 + wave * 64) * 8);
        }
        __syncthreads();
#pragma unroll
        for (int kk = 0; kk < 2; kk++) {
            h8 af[4], bg[4];
#pragma unroll
            for (int im = 0; im < 4; im++) {
                int row = wm + im * 16 + (lane & 15);
                int pc = (kk * 4 + (lane >> 4)) ^ (row & 7);
                af[im] = *(const h8*)(lA + row * 64 + pc * 8);
            }
#pragma unroll
            for (int in = 0; in < 4; in++) {
                int row = wn + in * 16 + (lane & 15);
                int pc = (kk * 4 + (lane >> 4)) ^ (row & 7);
                bg[in] = *(const h8*)(lB + row * 64 + pc * 8);
            }
#pragma unroll
            for (int im = 0; im < 4; im++)
#pragma unroll
                for (int in = 0; in < 4; in++)
                    acc[im][in] = MFMA(af[im], bg[in], acc[im][in]);
        }
    }
}

// ---------------- QKV GEMM: writes Q (prescaled), K [BH][T][64], V^T [BH][64][T] ----------------

__global__ __launch_bounds__(256) void qkv_gemm(const f16* __restrict__ A, const f16* __restrict__ Bt,
                                                const float* __restrict__ bias,
                                                f16* __restrict__ Qo, f16* __restrict__ Ko,
                                                f16* __restrict__ Vo) {
    __shared__ f16 lA[128 * 64], lB[128 * 64];
    f4 acc[4][4];
    const f4 zz = {0.f, 0.f, 0.f, 0.f};
#pragma unroll
    for (int i = 0; i < 4; i++)
#pragma unroll
        for (int j = 0; j < 4; j++) acc[i][j] = zz;

    const int swz = (blockIdx.x & 7) * 192 + (blockIdx.x >> 3);  // XCD-chunked (1536 = 8*192)
    const int nb = swz % 24, mb = swz / 24;
    gemm_core(A, Bt, 1024, mb * 128, nb * 128, lA, lB, acc);

    const int lane = threadIdx.x & 63, wave = threadIdx.x >> 6;
    const int wm = (wave >> 1) * 64, wn = (wave & 1) * 64;
#pragma unroll
    for (int im = 0; im < 4; im++) {
        int m4 = mb * 128 + wm + im * 16 + (lane >> 4) * 4;
        int b = m4 >> 11, t0 = m4 & 2047;
#pragma unroll
        for (int in = 0; in < 4; in++) {
            int n = nb * 128 + wn + in * 16 + (lane & 15);
            float bb = bias[n];
            int sec = n >> 10, cc = n & 1023, hh = cc >> 6, d = cc & 63;
            if (sec == 2) {
                h4 pv;
#pragma unroll
                for (int r = 0; r < 4; r++) pv[r] = (f16)(acc[im][in][r] + bb);
                *(h4*)(Vo + ((size_t)(b * 16 + hh) * 64 + d) * 2048 + t0) = pv;
            } else {
                f16* dst = sec ? Ko : Qo;
                float sc = sec ? 1.0f : QSCALE;  // Q prescaled for base-2 softmax
                size_t base = ((size_t)(b * 16 + hh) * 2048 + t0) * 64 + d;
#pragma unroll
                for (int r = 0; r < 4; r++)
                    dst[base + (size_t)r * 64] = (f16)((acc[im][in][r] + bb) * sc);
            }
        }
    }
}

// ---------------- Proj GEMM: f32 output + bias ----------------

__global__ __launch_bounds__(256) void proj_gemm(const f16* __restrict__ A, const f16* __restrict__ Bt,
                                                 const float* __restrict__ bias,
                                                 float* __restrict__ out) {
    __shared__ f16 lA[128 * 64], lB[128 * 64];
    f4 acc[4][4];
    const f4 zz = {0.f, 0.f, 0.f, 0.f};
#pragma unroll
    for (int i = 0; i < 4; i++)
#pragma unroll
        for (int j = 0; j < 4; j++) acc[i][j] = zz;

    const int swz = (blockIdx.x & 7) * 64 + (blockIdx.x >> 3);  // XCD-chunked (512 = 8*64)
    const int nb = swz & 7, mb = swz >> 3;
    gemm_core(A, Bt, 1024, mb * 128, nb * 128, lA, lB, acc);

    const int lane = threadIdx.x & 63, wave = threadIdx.x >> 6;
    const int wm = (wave >> 1) * 64, wn = (wave & 1) * 64;
#pragma unroll
    for (int im = 0; im < 4; im++) {
        int m4 = mb * 128 + wm + im * 16 + (lane >> 4) * 4;
#pragma unroll
        for (int in = 0; in < 4; in++) {
            int n = nb * 128 + wn + in * 16 + (lane & 15);
            float bb = bias[n];
#pragma unroll
            for (int r = 0; r < 4; r++)
                out[(size_t)(m4 + r) * 1024 + n] = acc[im][in][r] + bb;
        }
    }
}

// ---------------- Flash attention: 1-WAVE WORKGROUPS, LPT backfill ----------------
// Q(prescaled),K: [BH][2048][64] f16; Vg: [BH][64][2048] f16 (transposed); O: [B][2048][1024] f16
// Grid 4096 x 64 threads: 1 workgroup = 1 wave = 32 q-rows of one (b,h).
// Heaviest q-tiles dispatched FIRST (qt = 63 - blockIdx>>6) -> LPT scheduling: as light
// blocks retire the CP backfills, keeping CUs packed until the global tail.
// bh in low 6 bits -> bh%8 pins each bh's K/V panels (512KB) to one XCD L2 (8x512KB=4MB).
// Per-block private double-buffered LDS K-stage (2x4KB), per-wave vmcnt; ZERO barriers.
// Swapped QK^T (S^T = K.Q^T, mfma_32x32x16), in-register softmax (base-2, defer-max),
// P->A via cvt_pkrtz + permlane32_swap (HW-verified R9). Diagonal mask: kl > ln.

#define ASM_VMCNT(N) asm volatile("s_waitcnt vmcnt(" #N ")" ::: "memory")

__global__ __launch_bounds__(64) void attn_kernel(const f16* __restrict__ Q, const f16* __restrict__ K,
                                                  const f16* __restrict__ Vg, f16* __restrict__ O) {
    __shared__ f16 lK[2][2048];  // [buf][32 rows x 64]
    const int lane = threadIdx.x;
    const int hi = lane >> 5, ln = lane & 31;
    const int bh = blockIdx.x & 63;
    const int qt = 63 - (int)(blockIdx.x >> 6);  // heavy first (LPT)
    const int qw = qt * 32;
    const f16* Qb = Q + (size_t)bh * 2048 * 64;
    const f16* Kb = K + (size_t)bh * 2048 * 64;
    const f16* Vb = Vg + (size_t)bh * 64 * 2048;

    // hoist Q fragments (B-operand): Q[qw+ln][dd*16 + hi*8 .. +8]
    h8 qf[4];
#pragma unroll
    for (int dd = 0; dd < 4; dd++)
        qf[dd] = *(const h8*)(Qb + (size_t)(qw + ln) * 64 + dd * 16 + hi * 8);

    float mrun = -3e38f, lpart = 0.f;
    f16x y0, y1;
#pragma unroll
    for (int r = 0; r < 16; r++) { y0[r] = 0.f; y1[r] = 0.f; }

    const int nt = qt + 1;  // tiles of 32; last tile k0 == qw

    // prologue: stage tile 0 into buf 0 (4 x gload16 = 4KB)
#pragma unroll
    for (int i = 0; i < 4; i++) {
        int s = i * 64 + lane;
        int row = s >> 3;
        int gc = ((s & 7) ^ (row & 7)) * 8;
        gload16(Kb + (size_t)row * 64 + gc, &lK[0][i * 512]);
    }

    for (int it = 0; it < nt; it++) {
        const int k0 = it * 32;
        const int cb = it & 1, nb2 = (it + 1) & 1;

        if (it + 1 < nt) {
            // stage next tile into other buffer; loads stay in flight
#pragma unroll
            for (int i = 0; i < 4; i++) {
                int s = i * 64 + lane;
                int row = s >> 3;
                int gc = ((s & 7) ^ (row & 7)) * 8;
                gload16(Kb + (size_t)(k0 + 32 + row) * 64 + gc, &lK[nb2][i * 512]);
            }
            ASM_VMCNT(4);  // wait only this wave's current-tile 4 loads
        } else {
            ASM_VMCNT(0);
        }
        __builtin_amdgcn_sched_barrier(0);

        // V fragment loads issued EARLY (consumed at PV; QK+softmax hides L2 latency)
        h8 vf[2][2];
#pragma unroll
        for (int ks = 0; ks < 2; ks++)
#pragma unroll
            for (int j = 0; j < 2; j++)
                vf[ks][j] = *(const h8*)(Vb + (size_t)(j * 32 + ln) * 2048 + k0 + ks * 16 + hi * 8);

        // S^T = K.Q^T (A = K rows from private LDS, B = Q regs); lane owns q = qw+ln
        f16x s0;
#pragma unroll
        for (int r = 0; r < 16; r++) s0[r] = 0.f;
        __builtin_amdgcn_s_setprio(1);
#pragma unroll
        for (int dd = 0; dd < 4; dd++) {
            const int c = (dd * 2 + hi) ^ (ln & 7);  // swizzled 16B-chunk index
            h8 ka = *(const h8*)(&lK[cb][0] + ln * 64 + c * 8);
            s0 = MFMA32(ka, qf[dd], s0);
        }
        __builtin_amdgcn_s_setprio(0);

        if (it == nt - 1) {  // diagonal tile (k0 == qw): mask k-local kl > ln
#pragma unroll
            for (int r = 0; r < 16; r++) {
                int kl = (r & 3) + 8 * (r >> 2) + 4 * hi;
                if (kl > ln) s0[r] = -3e38f;
            }
        }

        // register-local softmax (base-2, defer-max)
        float vmax = s0[0];
#pragma unroll
        for (int r = 1; r < 16; r++) vmax = fmaxf(vmax, s0[r]);
        vmax = fmaxf(vmax, __shfl_xor(vmax, 32));
        if (!__all(vmax <= mrun + 8.0f)) {
            float mnew = fmaxf(mrun, vmax);
            float sc = fexp2(mrun - mnew);
            lpart *= sc;
            mrun = mnew;
#pragma unroll
            for (int r = 0; r < 16; r++) {
                float scy = __shfl(sc, (r & 3) + 8 * (r >> 2) + 4 * hi);
                y0[r] *= scy;
                y1[r] *= scy;
            }
        }
        float ls = 0.f;
#pragma unroll
        for (int r = 0; r < 16; r++) {
            float p = fexp2(s0[r] - mrun);
            s0[r] = p;
            ls += p;
        }
        lpart += ls;

        // P -> PV A-fragments: 8 cvt_pk + 4 permlane32_swap (no LDS; verified in R9)
        h8 pa[2];
        {
            unsigned a0 = pkh(s0[0], s0[1]), a1 = pkh(s0[2], s0[3]);
            unsigned b0 = pkh(s0[4], s0[5]), b1 = pkh(s0[6], s0[7]);
            plswap(a0, b0); plswap(a1, b1);
            u4 w0; w0[0] = a0; w0[1] = a1; w0[2] = b0; w0[3] = b1;
            pa[0] = __builtin_bit_cast(h8, w0);
            unsigned c0 = pkh(s0[8], s0[9]), c1 = pkh(s0[10], s0[11]);
            unsigned d0 = pkh(s0[12], s0[13]), d1 = pkh(s0[14], s0[15]);
            plswap(c0, d0); plswap(c1, d1);
            u4 w1; w1[0] = c0; w1[1] = c1; w1[2] = d0; w1[3] = d1;
            pa[1] = __builtin_bit_cast(h8, w1);
        }

        // Y += P V
        __builtin_amdgcn_s_setprio(1);
#pragma unroll
        for (int ks = 0; ks < 2; ks++) {
            y0 = MFMA32(pa[ks], vf[ks][0], y0);
            y1 = MFMA32(pa[ks], vf[ks][1], y1);
        }
        __builtin_amdgcn_s_setprio(0);
    }

    // epilogue: combine half-lane partials, normalize, store
    const int b = bh >> 4, hh = bh & 15;
    float lT = lpart + __shfl_xor(lpart, 32);
    float inv = 1.0f / lT;
#pragma unroll
    for (int r = 0; r < 16; r++) {
        int crow = (r & 3) + 8 * (r >> 2) + 4 * hi;
        float invr = __shfl(inv, crow);
        size_t base = ((size_t)(b * 2048 + qw + crow)) * 1024 + hh * 64 + ln;
        O[base] = (f16)(y0[r] * invr);
        O[base + 32] = (f16)(y1[r] * invr);
    }
}

// ---------------- launch ----------------

extern "C" void kernel_launch(void* const* d_in, const int* in_sizes, int n_in,
                              void* d_out, int out_size, void* d_ws, size_t ws_size,
                              hipStream_t stream) {
    const float* x      = (const float*)d_in[0];
    const float* W_attn = (const float*)d_in[1];
    const float* b_attn = (const float*)d_in[2];
    const float* W_proj = (const float*)d_in[3];
    const float* b_proj = (const float*)d_in[4];
    float* out = (float*)d_out;

    char* ws = (char*)d_ws;
    f16* xb  = (f16*)ws;                                   // 16 MB (reused as attn out)
    f16* Wat = (f16*)(ws + 16777216);                      // 6 MB
    f16* Wpt = (f16*)(ws + 16777216 + 6291456);            // 2 MB
    f16* Vt  = (f16*)(ws + 16777216 + 6291456 + 2097152);  // 16 MB
    f16* Qs  = (f16*)d_out;                                // scratch: first 16 MB of out
    f16* Ks  = (f16*)((char*)d_out + 16777216);            // scratch: second 16 MB of out

    cvt_f16_kernel<<<4096, 256, 0, stream>>>(x, xb, 1048576);
    transpose_cvt<<<dim3(96, 32), dim3(32, 8), 0, stream>>>(W_attn, Wat, 1024, 3072);
    transpose_cvt<<<dim3(32, 32), dim3(32, 8), 0, stream>>>(W_proj, Wpt, 1024, 1024);
    qkv_gemm<<<1536, 256, 0, stream>>>(xb, Wat, b_attn, Qs, Ks, Vt);
    attn_kernel<<<4096, 64, 0, stream>>>(Qs, Ks, Vt, xb);
    proj_gemm<<<512, 256, 0, stream>>>(xb, Wpt, b_proj, out);
}